// Round 2
// baseline (127602.173 us; speedup 1.0000x reference)
//
#include <hip/hip_runtime.h>
#include <hip/hip_bf16.h>
#include <cstdint>
#include <cstddef>

#define T_DIM 512
#define B_DIM 256
#define D_DIM 256
#define H_DIM 512
#define O_DIM 256
#define NSTEP 10

__device__ __forceinline__ unsigned short f2bf(float f) {
    __hip_bfloat16 b = __float2bfloat16(f);   // RNE
    return *reinterpret_cast<unsigned short*>(&b);
}

// ---------------- transposes (tiny) ----------------
__global__ void k_transpose(const float* __restrict__ W_ih,
                            const float* __restrict__ W_out,
                            float* __restrict__ wihT,   // [256][512] d-major
                            float* __restrict__ woutT)  // [512][256] h-major
{
    int idx = blockIdx.x * blockDim.x + threadIdx.x;
    if (idx < 256 * 512) {
        int d = idx >> 9, h = idx & 511;
        wihT[d * 512 + h] = W_ih[h * 257 + d];   // W_ih row length = 257
    } else if (idx < 256 * 512 + 512 * 256) {
        int j = idx - 256 * 512;
        int h = j >> 8, o = j & 255;
        woutT[h * 256 + o] = W_out[o * 512 + h];
    }
}

// ---------------- xc = x @ W_ih[:, :D].T + (b_ih + b_hh) ----------------
// (identical arithmetic to round 0 — only used when ws is large enough)
__global__ __launch_bounds__(512) void k_xc(
    const float* __restrict__ x,     // [T*B, 256]
    const float* __restrict__ wihT,  // [256][512]
    const float* __restrict__ b_ih,
    const float* __restrict__ b_hh,
    float* __restrict__ xc)          // [T*B, 512]
{
    __shared__ float xl[16][256];
    const int tid = threadIdx.x;
    const int tb0 = blockIdx.x * 16;
    for (int i = tid; i < 16 * 256; i += 512)
        xl[i >> 8][i & 255] = x[(size_t)tb0 * 256 + i];
    __syncthreads();
    const int h = tid;
    float acc[16];
#pragma unroll
    for (int r = 0; r < 16; ++r) acc[r] = 0.f;
    for (int d = 0; d < 256; d += 4) {
        const float wv0 = wihT[(d + 0) * 512 + h];
        const float wv1 = wihT[(d + 1) * 512 + h];
        const float wv2 = wihT[(d + 2) * 512 + h];
        const float wv3 = wihT[(d + 3) * 512 + h];
#pragma unroll
        for (int r = 0; r < 16; ++r) {
            const float4 xv = *(const float4*)&xl[r][d];
            acc[r] += xv.x * wv0;
            acc[r] += xv.y * wv1;
            acc[r] += xv.z * wv2;
            acc[r] += xv.w * wv3;
        }
    }
    const float bias = b_ih[h] + b_hh[h];
    for (int r = 0; r < 16; ++r)
        xc[(size_t)(tb0 + r) * 512 + h] = acc[r] + bias;
}

// ---------------- sequential ACT recurrence ----------------
// 128 blocks x 512 threads; block owns 2 batch rows; thread owns column h = tid
// for BOTH rows (guarantees each W_hh cacheline is read exactly once per block
// per ponder step). W_hh streamed row-major (no transpose), register
// double-buffered float4 prefetch; s broadcast from LDS.
// Arithmetic (summation trees, fma contraction shapes, tanhf/expf) reproduces
// the round-0 kernel bitwise to keep every halting decision identical.
__global__ __launch_bounds__(512) void k_recur2(
    const float* __restrict__ xc,    // [T*B,512] or null -> compute in-loop
    const float* __restrict__ x,     // [T,B,256]
    const float* __restrict__ wihT,  // [256][512]
    const float* __restrict__ W_hh,  // [512][512] row-major [h][k]
    const float* __restrict__ W_ih,  // flag col at [h*257+256]
    const float* __restrict__ w_halt,
    const float* __restrict__ b_ih,
    const float* __restrict__ b_hh,
    const float* __restrict__ b_halt,
    float* out,                      // d_out (y region reused as bf16 s_acc)
    float* __restrict__ psum_g)      // [T*B]
{
    __shared__ __align__(16) float sb[2][2][512];  // s ping-pong, per row
    __shared__ float xl[2][256];
    __shared__ float whalt_l[512];
    __shared__ float flag_l[512];
    __shared__ float bias_l[512];
    __shared__ float red[2][2][8];  // [parity][row][wave]

    const int tid = threadIdx.x;   // == h
    const int h = tid;
    const int b0 = blockIdx.x * 2;
    const int wr = tid >> 6;       // wave 0..7
    const int lane = tid & 63;

    whalt_l[h] = w_halt[h];
    flag_l[h] = W_ih[h * 257 + 256];
    bias_l[h] = b_ih[h] + b_hh[h];
    sb[0][0][h] = 0.f;
    sb[0][1][h] = 0.f;
    __syncthreads();

    const float bh = b_halt[0];
    const float THR = 1.0f - 0.01f;
    unsigned short* sacc_out = (unsigned short*)out;  // bf16 staging in y region
    float* rho_out = out + (size_t)T_DIM * B_DIM * O_DIM;
    float* n_out = rho_out + (size_t)T_DIM * B_DIM;

    const float4* w4 = (const float4*)(W_hh + (size_t)h * H_DIM);
    const float wE_h = whalt_l[h & 510];
    const float wO_h = whalt_l[h | 1];
    const bool evenlane = (lane & 1) == 0;

    int cur = 0;
    for (int t = 0; t < T_DIM; ++t) {
        float xcv[2];
        if (xc) {
            xcv[0] = xc[((size_t)t * B_DIM + b0) * 512 + h];
            xcv[1] = xc[((size_t)t * B_DIM + b0 + 1) * 512 + h];
        } else {
            // stage x rows (2 x 256 floats, coalesced)
            xl[tid >> 8][tid & 255] =
                x[((size_t)t * B_DIM + b0 + (tid >> 8)) * D_DIM + (tid & 255)];
            __syncthreads();
            float a0 = 0.f, a1 = 0.f;
#pragma unroll 4
            for (int d = 0; d < D_DIM; ++d) {
                const float wv = wihT[d * 512 + h];
                a0 += xl[0][d] * wv;   // same per-row ascending-d fma chain as r0
                a1 += xl[1][d] * wv;
            }
            xcv[0] = a0 + bias_l[h];
            xcv[1] = a1 + bias_l[h];
        }

        float sacc0 = 0.f, sacc1 = 0.f;
        float hsum[2] = {0.f, 0.f}, runf[2] = {1.f, 1.f};
        float stepsf[2] = {0.f, 0.f}, remf[2] = {0.f, 0.f}, psum[2] = {0.f, 0.f};

        for (int nstep = 0; nstep < NSTEP; ++nstep) {
            const int par = nstep & 1;
            float pre0 = xcv[0], pre1 = xcv[1];
            if (nstep == 0) { pre0 += flag_l[h]; pre1 += flag_l[h]; }

            const float4* s40 = (const float4*)sb[cur][0];
            const float4* s41 = (const float4*)sb[cur][1];

            // K-loop: 16 chunks of 32 floats, A/B register double-buffer.
            // Per-row single fma chain, ascending k (bitwise == round 0).
            float4 wbA[8], wbB[8];
#pragma unroll
            for (int i = 0; i < 8; ++i) wbA[i] = w4[i];
            for (int c = 0; c < 16; c += 2) {
#pragma unroll
                for (int i = 0; i < 8; ++i) wbB[i] = w4[(c + 1) * 8 + i];
#pragma unroll
                for (int i = 0; i < 8; ++i) {
                    const float4 wv = wbA[i];
                    const float4 sv0 = s40[c * 8 + i];
                    const float4 sv1 = s41[c * 8 + i];
                    pre0 += sv0.x * wv.x; pre1 += sv1.x * wv.x;
                    pre0 += sv0.y * wv.y; pre1 += sv1.y * wv.y;
                    pre0 += sv0.z * wv.z; pre1 += sv1.z * wv.z;
                    pre0 += sv0.w * wv.w; pre1 += sv1.w * wv.w;
                }
                if (c + 2 < 16) {
#pragma unroll
                    for (int i = 0; i < 8; ++i) wbA[i] = w4[(c + 2) * 8 + i];
                }
#pragma unroll
                for (int i = 0; i < 8; ++i) {
                    const float4 wv = wbB[i];
                    const float4 sv0 = s40[(c + 1) * 8 + i];
                    const float4 sv1 = s41[(c + 1) * 8 + i];
                    pre0 += sv0.x * wv.x; pre1 += sv1.x * wv.x;
                    pre0 += sv0.y * wv.y; pre1 += sv1.y * wv.y;
                    pre0 += sv0.z * wv.z; pre1 += sv1.z * wv.z;
                    pre0 += sv0.w * wv.w; pre1 += sv1.w * wv.w;
                }
            }

            const float sn0 = tanhf(pre0);
            const float sn1 = tanhf(pre1);
            sb[cur ^ 1][0][h] = sn0;
            sb[cur ^ 1][1][h] = sn1;

            // halt dot: reproduce round-0 reduction tree exactly.
            // leaf = snE*wE + snO*wO (same source shape -> same contraction),
            // 5 butterfly levels (masks 2..32) = hpair bits 0..4, lane0 keeps
            // left-first bracketing; wave sums recombined as ((W0+W1)+W2)+W3.
            {
                const float snP0 = __shfl_xor(sn0, 1, 64);
                const float snP1 = __shfl_xor(sn1, 1, 64);
                const float snE0 = evenlane ? sn0 : snP0;
                const float snO0 = evenlane ? snP0 : sn0;
                const float snE1 = evenlane ? sn1 : snP1;
                const float snO1 = evenlane ? snP1 : sn1;
                float part0 = snE0 * wE_h + snO0 * wO_h;
                float part1 = snE1 * wE_h + snO1 * wO_h;
#pragma unroll
                for (int m = 2; m <= 32; m <<= 1) {
                    part0 += __shfl_xor(part0, m, 64);
                    part1 += __shfl_xor(part1, m, 64);
                }
                if (lane == 0) {
                    red[par][0][wr] = part0;
                    red[par][1][wr] = part1;
                }
            }
            __syncthreads();

            bool anyrun = false;
            float pp[2];
#pragma unroll
            for (int r = 0; r < 2; ++r) {
                const float* rr = red[par][r];
                const float Wa = rr[0] + rr[1];
                const float Wb = rr[2] + rr[3];
                const float Wc = rr[4] + rr[5];
                const float Wd = rr[6] + rr[7];
                const float dot = ((Wa + Wb) + Wc) + Wd;
                const float z = dot + bh;
                const float hn = 1.f / (1.f + expf(-z));
                const float ns = hsum[r] + hn;
                const float stop = (ns >= THR) ? runf[r] : 0.f;
                const float still = runf[r] - stop;
                const float rem = (1.f - hsum[r]) * stop;
                const float p = hn * still + rem;
                pp[r] = p;
                psum[r] += p;
                stepsf[r] += runf[r];   // old running, matches reference order
                remf[r] += rem;
                hsum[r] = ns;
                runf[r] = still;
                anyrun = anyrun || (still != 0.f);
            }
            sacc0 += pp[0] * sn0;
            sacc1 += pp[1] * sn1;
            cur ^= 1;
            if (!anyrun) break;  // uniform across the block
        }

        // epilogue: s(next t) = s_acc; store bf16 s_acc, psum, rho, n
        sb[cur][0][h] = sacc0;
        sb[cur][1][h] = sacc1;
        {
            const size_t base0 = ((size_t)t * B_DIM + b0) * 512 + h;
            sacc_out[base0] = f2bf(sacc0);
            sacc_out[base0 + 512] = f2bf(sacc1);
        }
        if (tid == 0) {
#pragma unroll
            for (int r = 0; r < 2; ++r) {
                psum_g[t * B_DIM + b0 + r] = psum[r];
                rho_out[t * B_DIM + b0 + r] = stepsf[r] + remf[r];
                n_out[t * B_DIM + b0 + r] = stepsf[r];
            }
        }
        __syncthreads();
    }
}

// ---------------- y = s_acc @ W_out.T + psum * b_out ----------------
// Reads bf16 s_acc from the y region of d_out, overwrites same rows with y.
__global__ __launch_bounds__(256) void k_y(
    const float* __restrict__ woutT,  // [512][256]
    const float* __restrict__ b_out,
    const float* __restrict__ psum_g,
    float* out)
{
    __shared__ float sl[16][512];
    __shared__ float pl[16];
    const int tid = threadIdx.x;
    const int tb0 = blockIdx.x * 16;
    const unsigned short* sacc = (const unsigned short*)out;
    for (int i = tid; i < 16 * 512; i += 256) {
        unsigned int u = sacc[(size_t)tb0 * 512 + i];
        u <<= 16;
        sl[i >> 9][i & 511] = __uint_as_float(u);
    }
    if (tid < 16) pl[tid] = psum_g[tb0 + tid];
    __syncthreads();
    const int o = tid;
    float acc[16];
#pragma unroll
    for (int r = 0; r < 16; ++r) acc[r] = 0.f;
    for (int hh = 0; hh < 512; hh += 4) {
        const float wv0 = woutT[(hh + 0) * 256 + o];
        const float wv1 = woutT[(hh + 1) * 256 + o];
        const float wv2 = woutT[(hh + 2) * 256 + o];
        const float wv3 = woutT[(hh + 3) * 256 + o];
#pragma unroll
        for (int r = 0; r < 16; ++r) {
            const float4 sv = *(const float4*)&sl[r][hh];
            acc[r] += sv.x * wv0;
            acc[r] += sv.y * wv1;
            acc[r] += sv.z * wv2;
            acc[r] += sv.w * wv3;
        }
    }
    const float bo = b_out[o];
    for (int r = 0; r < 16; ++r)
        out[(size_t)(tb0 + r) * 256 + o] = acc[r] + pl[r] * bo;
}

extern "C" void kernel_launch(void* const* d_in, const int* in_sizes, int n_in,
                              void* d_out, int out_size, void* d_ws, size_t ws_size,
                              hipStream_t stream) {
    const float* x = (const float*)d_in[0];
    const float* W_ih = (const float*)d_in[1];
    const float* b_ih = (const float*)d_in[2];
    const float* W_hh = (const float*)d_in[3];
    const float* b_hh = (const float*)d_in[4];
    const float* W_halt = (const float*)d_in[5];
    const float* b_halt = (const float*)d_in[6];
    const float* W_out = (const float*)d_in[7];
    const float* b_out = (const float*)d_in[8];
    float* out = (float*)d_out;

    char* ws = (char*)d_ws;
    float* wihT = (float*)ws;                                 // 512 KB
    float* woutT = (float*)(ws + (512u << 10));               // 512 KB
    float* psum = (float*)(ws + (1u << 20));                  // 512 KB
    float* xc = (float*)(ws + (1u << 20) + (512u << 10));     // 268.4 MB
    const size_t need_xc =
        (size_t)(1u << 20) + (512u << 10) + (size_t)T_DIM * B_DIM * H_DIM * 4;
    const bool use_xc = (ws_size >= need_xc);

    hipLaunchKernelGGL(k_transpose, dim3(1024), dim3(256), 0, stream,
                       W_ih, W_out, wihT, woutT);
    if (use_xc)
        hipLaunchKernelGGL(k_xc, dim3((T_DIM * B_DIM) / 16), dim3(512), 0, stream,
                           x, wihT, b_ih, b_hh, xc);
    hipLaunchKernelGGL(k_recur2, dim3(B_DIM / 2), dim3(512), 0, stream,
                       use_xc ? xc : (const float*)nullptr, x, wihT, W_hh, W_ih,
                       W_halt, b_ih, b_hh, b_halt, out, psum);
    hipLaunchKernelGGL(k_y, dim3((T_DIM * B_DIM) / 16), dim3(256), 0, stream,
                       woutT, b_out, psum, out);
}

// Round 3
// 28323.547 us; speedup vs baseline: 4.5052x; 4.5052x over previous
//
#include <hip/hip_runtime.h>
#include <hip/hip_bf16.h>
#include <cstdint>
#include <cstddef>

#define T_DIM 512
#define B_DIM 256
#define D_DIM 256
#define H_DIM 512
#define O_DIM 256
#define NSTEP 10
#define WIN 16

__device__ __forceinline__ unsigned short f2bf(float f) {
    __hip_bfloat16 b = __float2bfloat16(f);   // RNE
    return *reinterpret_cast<unsigned short*>(&b);
}

// ---------------- transposes (tiny) ----------------
__global__ void k_transpose(const float* __restrict__ W_ih,
                            const float* __restrict__ W_out,
                            float* __restrict__ wihT,   // [256][512] d-major
                            float* __restrict__ woutT)  // [512][256] h-major
{
    int idx = blockIdx.x * blockDim.x + threadIdx.x;
    if (idx < 256 * 512) {
        int d = idx >> 9, h = idx & 511;
        wihT[d * 512 + h] = W_ih[h * 257 + d];   // W_ih row length = 257
    } else if (idx < 256 * 512 + 512 * 256) {
        int j = idx - 256 * 512;
        int h = j >> 8, o = j & 255;
        woutT[h * 256 + o] = W_out[o * 512 + h];
    }
}

// ---------------- sequential ACT recurrence, W_hh persistent in VGPRs ------
// 256 blocks x 1024 threads; block b owns batch row b; exactly 1 block/CU
// (VGPR-forced). Thread (h = tid&511, kh = tid>>9) permanently holds
// W_hh[h][kh*256 .. kh*256+256) in 64 float4 registers (static indexing only).
// Per ponder step: dot via LDS-broadcast s + register W; two-half combine in
// LDS; wave butterfly for the halt dot. xc computed in-kernel in windows of
// 16 t (LDS-staged x, wihT streamed once per window). All fp32; halting
// scalars replicated uniformly on every thread (uniform break, no divergent
// barriers).
__global__ __launch_bounds__(1024) void k_recur3(
    const float* __restrict__ x,      // [T,B,256]
    const float* __restrict__ wihT,   // [256][512] d-major
    const float* __restrict__ W_hh,   // [512][512] row-major
    const float* __restrict__ W_ih,   // flag col at [h*257+256]
    const float* __restrict__ w_halt,
    const float* __restrict__ b_ih,
    const float* __restrict__ b_hh,
    const float* __restrict__ b_halt,
    float* out,                       // d_out (y region reused as bf16 s_acc)
    float* __restrict__ psum_g)       // [T*B]
{
    __shared__ __align__(16) float sb[2][H_DIM];     // s ping-pong
    __shared__ __align__(16) float xw[WIN][D_DIM];   // x window
    __shared__ __align__(16) float xcw[WIN][H_DIM];  // xc window
    __shared__ float part1[H_DIM];                   // kh=1 partial dots
    __shared__ float whalt_l[H_DIM];
    __shared__ float flag_l[H_DIM];
    __shared__ float bias_l[H_DIM];
    __shared__ float red[8];                         // wave sums (waves 0..7)

    const int tid = threadIdx.x;
    const int h = tid & 511;
    const int kh = tid >> 9;
    const int b = blockIdx.x;
    const int wave = tid >> 6;
    const int lane = tid & 63;

    if (!kh) {
        whalt_l[h] = w_halt[h];
        flag_l[h] = W_ih[h * 257 + 256];
        bias_l[h] = b_ih[h] + b_hh[h];
        sb[0][h] = 0.f;
    }

    // Persistent W slice: 64 float4 = 256 VGPRs. All accesses static.
    float4 w4[64];
    {
        const float4* src = (const float4*)(W_hh + (size_t)h * H_DIM + kh * 256);
#pragma unroll
        for (int j = 0; j < 64; ++j) w4[j] = src[j];
    }
    __syncthreads();

    const float bh = b_halt[0];
    const float THR = 1.0f - 0.01f;
    unsigned short* sacc_out = (unsigned short*)out;  // bf16 staging in y region
    float* rho_out = out + (size_t)T_DIM * B_DIM * O_DIM;
    float* n_out = rho_out + (size_t)T_DIM * B_DIM;

    int cur = 0;
    for (int t = 0; t < T_DIM; ++t) {
        const int tw = t & (WIN - 1);
        if (tw == 0) {
            // stage x[t..t+WIN)[b][:]  (coalesced; 4 iters)
            for (int i = tid; i < WIN * D_DIM; i += 1024)
                xw[i >> 8][i & 255] =
                    x[((size_t)(t + (i >> 8)) * B_DIM + b) * D_DIM + (i & 255)];
            __syncthreads();
            // xcw[j][h] = sum_d xw[j][d] * wihT[d][h] + bias ; thread does
            // j = kh*8..kh*8+7. wihT coalesced across h; xw broadcast.
            float xa[8];
#pragma unroll
            for (int jj = 0; jj < 8; ++jj) xa[jj] = 0.f;
            for (int d = 0; d < 256; d += 4) {
                const float w0 = wihT[(d + 0) * 512 + h];
                const float w1 = wihT[(d + 1) * 512 + h];
                const float w2 = wihT[(d + 2) * 512 + h];
                const float w3 = wihT[(d + 3) * 512 + h];
#pragma unroll
                for (int jj = 0; jj < 8; ++jj) {
                    const float4 xv = *(const float4*)&xw[kh * 8 + jj][d];
                    xa[jj] += xv.x * w0;
                    xa[jj] += xv.y * w1;
                    xa[jj] += xv.z * w2;
                    xa[jj] += xv.w * w3;
                }
            }
#pragma unroll
            for (int jj = 0; jj < 8; ++jj)
                xcw[kh * 8 + jj][h] = xa[jj] + bias_l[h];
            __syncthreads();
        }

        float sacc_v = 0.f;
        float hsum = 0.f, runf = 1.f, stepsf = 0.f, remf = 0.f, psum_v = 0.f;

        for (int nstep = 0; nstep < NSTEP; ++nstep) {
            // ---- main dot: register W x LDS-broadcast s ----
            const float4* s4 = (const float4*)sb[cur] + kh * 64;
            float4 a0{0.f, 0.f, 0.f, 0.f}, a1 = a0, a2 = a0, a3 = a0;
#pragma unroll
            for (int j = 0; j < 16; ++j) {
                float4 sv, wv;
                sv = s4[j * 4 + 0]; wv = w4[j * 4 + 0];
                a0.x += sv.x * wv.x; a0.y += sv.y * wv.y;
                a0.z += sv.z * wv.z; a0.w += sv.w * wv.w;
                sv = s4[j * 4 + 1]; wv = w4[j * 4 + 1];
                a1.x += sv.x * wv.x; a1.y += sv.y * wv.y;
                a1.z += sv.z * wv.z; a1.w += sv.w * wv.w;
                sv = s4[j * 4 + 2]; wv = w4[j * 4 + 2];
                a2.x += sv.x * wv.x; a2.y += sv.y * wv.y;
                a2.z += sv.z * wv.z; a2.w += sv.w * wv.w;
                sv = s4[j * 4 + 3]; wv = w4[j * 4 + 3];
                a3.x += sv.x * wv.x; a3.y += sv.y * wv.y;
                a3.z += sv.z * wv.z; a3.w += sv.w * wv.w;
            }
            const float h0 = (a0.x + a0.y) + (a0.z + a0.w);
            const float h1 = (a1.x + a1.y) + (a1.z + a1.w);
            const float h2 = (a2.x + a2.y) + (a2.z + a2.w);
            const float h3 = (a3.x + a3.y) + (a3.z + a3.w);
            const float pd = (h0 + h1) + (h2 + h3);

            if (kh) part1[h] = pd;
            __syncthreads();   // A: part1 ready; sb[cur] fully consumed

            float sn = 0.f;
            if (!kh) {
                float base = xcw[tw][h];
                if (nstep == 0) base += flag_l[h];
                const float pre = (base + pd) + part1[h];
                sn = tanhf(pre);
                sb[cur ^ 1][h] = sn;
                float part = sn * whalt_l[h];
#pragma unroll
                for (int m = 1; m < 64; m <<= 1) part += __shfl_xor(part, m, 64);
                if (lane == 0) red[wave] = part;
            }
            __syncthreads();   // B: s-next + red ready

            // ---- halting scalars, replicated uniformly on all 1024 threads ----
            const float dotv = ((red[0] + red[1]) + (red[2] + red[3])) +
                               ((red[4] + red[5]) + (red[6] + red[7]));
            const float z = dotv + bh;
            const float hn = 1.f / (1.f + expf(-z));
            const float ns = hsum + hn;
            const float stop = (ns >= THR) ? runf : 0.f;
            const float still = runf - stop;
            const float rem = (1.f - hsum) * stop;
            const float p = hn * still + rem;
            if (!kh) sacc_v += p * sn;
            psum_v += p;
            stepsf += runf;   // old running, matches reference order
            remf += rem;
            hsum = ns;
            runf = still;
            cur ^= 1;
            if (still == 0.f) break;   // uniform across block
        }

        // epilogue: s(next t) = s_acc; bf16-stage s_acc; store psum/rho/n
        if (!kh) {
            sb[cur][h] = sacc_v;
            const size_t base = ((size_t)t * B_DIM + b) * (size_t)H_DIM + h;
            sacc_out[base] = f2bf(sacc_v);
        }
        if (tid == 0) {
            psum_g[t * B_DIM + b] = psum_v;
            rho_out[t * B_DIM + b] = stepsf + remf;
            n_out[t * B_DIM + b] = stepsf;
        }
        __syncthreads();   // C: protects sb[cur] overwrite + window reuse
    }
}

// ---------------- y = s_acc @ W_out.T + psum * b_out ----------------
// Reads bf16 s_acc from the y region of d_out, overwrites same rows with y.
__global__ __launch_bounds__(256) void k_y(
    const float* __restrict__ woutT,  // [512][256]
    const float* __restrict__ b_out,
    const float* __restrict__ psum_g,
    float* out)
{
    __shared__ float sl[16][512];
    __shared__ float pl[16];
    const int tid = threadIdx.x;
    const int tb0 = blockIdx.x * 16;
    const unsigned short* sacc = (const unsigned short*)out;
    for (int i = tid; i < 16 * 512; i += 256) {
        unsigned int u = sacc[(size_t)tb0 * 512 + i];
        u <<= 16;
        sl[i >> 9][i & 511] = __uint_as_float(u);
    }
    if (tid < 16) pl[tid] = psum_g[tb0 + tid];
    __syncthreads();
    const int o = tid;
    float acc[16];
#pragma unroll
    for (int r = 0; r < 16; ++r) acc[r] = 0.f;
    for (int hh = 0; hh < 512; hh += 4) {
        const float wv0 = woutT[(hh + 0) * 256 + o];
        const float wv1 = woutT[(hh + 1) * 256 + o];
        const float wv2 = woutT[(hh + 2) * 256 + o];
        const float wv3 = woutT[(hh + 3) * 256 + o];
#pragma unroll
        for (int r = 0; r < 16; ++r) {
            const float4 sv = *(const float4*)&sl[r][hh];
            acc[r] += sv.x * wv0;
            acc[r] += sv.y * wv1;
            acc[r] += sv.z * wv2;
            acc[r] += sv.w * wv3;
        }
    }
    const float bo = b_out[o];
    for (int r = 0; r < 16; ++r)
        out[(size_t)(tb0 + r) * 256 + o] = acc[r] + pl[r] * bo;
}

extern "C" void kernel_launch(void* const* d_in, const int* in_sizes, int n_in,
                              void* d_out, int out_size, void* d_ws, size_t ws_size,
                              hipStream_t stream) {
    const float* x = (const float*)d_in[0];
    const float* W_ih = (const float*)d_in[1];
    const float* b_ih = (const float*)d_in[2];
    const float* W_hh = (const float*)d_in[3];
    const float* b_hh = (const float*)d_in[4];
    const float* W_halt = (const float*)d_in[5];
    const float* b_halt = (const float*)d_in[6];
    const float* W_out = (const float*)d_in[7];
    const float* b_out = (const float*)d_in[8];
    float* out = (float*)d_out;

    char* ws = (char*)d_ws;
    float* wihT = (float*)ws;                        // 512 KB
    float* woutT = (float*)(ws + (512u << 10));      // 512 KB
    float* psum = (float*)(ws + (1u << 20));         // 512 KB

    hipLaunchKernelGGL(k_transpose, dim3(1024), dim3(256), 0, stream,
                       W_ih, W_out, wihT, woutT);
    hipLaunchKernelGGL(k_recur3, dim3(B_DIM), dim3(1024), 0, stream,
                       x, wihT, W_hh, W_ih, W_halt, b_ih, b_hh, b_halt,
                       out, psum);
    hipLaunchKernelGGL(k_y, dim3((T_DIM * B_DIM) / 16), dim3(256), 0, stream,
                       woutT, b_out, psum, out);
}